// Round 1
// baseline (308.879 us; speedup 1.0000x reference)
//
#include <hip/hip_runtime.h>
#include <cstdint>

// ===========================================================================
// KWS_LSTM_bmm — exact integer reformulation, fp32-faithful quant decisions.
// R15: 4 rows/WG x 512 WGs -> 2 WGs/CU (LDS 74.4 KB) to fill latency slack.
//   R14 post-mortem: no pipe saturated (LDS ~58%, MFMA 27%, VALU ~19% pure);
//   step time dominated by the serial chain w/ 1 WG/CU. Changes:
//   * grid 512 = 8 n x 64 four-row batch tiles; 2 independent WGs per CU.
//   * xq rows packed at 48 B (16B-aligned b128; k=40..63 spill hits zeroed
//     B weights); fcred/vout alias xq (dead at finFC) -> LDS 74416 B.
//   * A-row remap bmap(c)=c>>2: every lane's single ew item lives in acc
//     reg 0 -> no cndmasks; x-shadow *32+bias on elem 0 only.
// Exactness: every lattice chain bit-exact in fp32 (numerators < 2^24);
// sigmoid/tanh exact byte LUTs (fast fp32 + 0.498-margin fp64 fallback).
// ===========================================================================

typedef int v4i __attribute__((ext_vector_type(4)));

#define SEQn 101
#define BLK  832              // 13 waves
#define HST  288              // h row stride (balanced bank groups on b128)
#define HSLOT 1152            // 4 rows
#define XROW 48               // xq row stride (16B-aligned, zero-B spill)
#define SIG_OFF 22720
#define SIG_SZ  41152         // sigmoid q-LUT (idx >= 41152 saturates to 127)
#define TMAX 10527            // |tanh| saturation index

// LDS layout (tables low: gathers fold base into 16-bit ds offset-imm)
#define L_SIGT  0             // u8[41152]
#define L_TANH  41152         // i8[10528]  |tanh| magnitude table
#define L_TANC  51680         // float[255] (1024 B slot)
#define L_XQ    52704         // i8: 101*192 + 16 pad = 19408 B
#define L_FCRED 52704         // int[64]   (aliases XQ; XQ dead at finFC)
#define L_VOUT  52960         // float[8]  (aliases XQ)
#define L_HBUF  72112         // i8[2][HSLOT] = 2304 B
#define L_TOTAL 74416

__device__ __forceinline__ int q8f(float v) {        // rint(clip(v*128, ±127))
    float t = fminf(fmaxf(v * 128.0f, -127.0f), 127.0f);
    return (int)rintf(t);
}

// fp32-faithful qp(x, a1=128, 8) on raw inputs
__device__ __forceinline__ int xq_f32(float xv) {
    float ax  = fabsf(xv);
    float d   = ax - 128.0f;
    float u   = ax - fabsf(d);
    float v   = u + 128.0f;
    float p   = 0.5f * v;
    float x01 = p * 0.0078125f;
    x01 = fminf(x01, 0.9921875f);
    int q = (int)rintf(x01 * 128.0f);
    return (xv < 0.0f) ? -q : q;
}

// ---------------- kernel 1: weight quant + K64 B-fragment packing ----------
__global__ __launch_bounds__(256) void prep_w(const float* __restrict__ w_ih,
                                              const float* __restrict__ w_hh,
                                              unsigned long long* __restrict__ wsl) {
    int o = blockIdx.x * 256 + threadIdx.x;          // 0..266239
    int h = o & 1; int l = (o >> 1) & 63; int r = o >> 7;
    int ch = r % 5; r /= 5;
    int G = r & 3;  r >>= 2;
    int t = r % 13; int n = r / 13;
    int q = l >> 4, cc = l & 15;
    int colW = 16 * t + cc;
    unsigned long long pack = 0ull;
    if (colW < 200) {
        int col = G * 200 + colW;
        #pragma unroll
        for (int jj = 0; jj < 8; ++jj) {
            int k_in = 16 * q + 8 * h + jj;
            int v = 0;
            if (ch == 0) { if (k_in < 40) v = q8f(w_ih[(n * 40 + k_in) * 800 + col]); }
            else { int kk = 64 * (ch - 1) + k_in; if (kk < 200) v = q8f(w_hh[(n * 200 + kk) * 800 + col]); }
            pack |= (unsigned long long)((unsigned)v & 0xffu) << (8 * jj);
        }
    }
    wsl[o] = pack;
}

// ---------------- kernel 2: persistent LSTM ---------------------------------
__global__ __launch_bounds__(BLK) void lstm_k(const float* __restrict__ x,
                                              const float* __restrict__ b_ih,
                                              const float* __restrict__ b_hh,
                                              const float* __restrict__ fw,
                                              const float* __restrict__ fb,
                                              const unsigned long long* __restrict__ wsl,
                                              float* __restrict__ out) {
    __shared__ __align__(16) unsigned char smem[L_TOTAL];
    unsigned char* sigt  = smem + L_SIGT;
    signed char*   tanh8 = (signed char*)(smem + L_TANH);
    float*         tanc  = (float*)(smem + L_TANC);
    int*           fcred = (int*)(smem + L_FCRED);
    float*         vout  = (float*)(smem + L_VOUT);
    signed char*   xq    = (signed char*)(smem + L_XQ);
    signed char*   hbuf  = (signed char*)(smem + L_HBUF);

    const int tid  = threadIdx.x;
    const int n    = blockIdx.x >> 6;                // 0..7
    const int b0   = (blockIdx.x & 63) * 4;          // batch base (4 rows/WG)
    const int W    = tid >> 6;                       // wave 0..12, col-tile W
    const int lane = tid & 63;
    const int q    = lane >> 4;                      // quad
    const int c    = lane & 15;                      // A row idx / B col
    const int arow = c >> 2;                         // batch row held by A row c
    const int colW = 16 * W + c;
    const bool gok = (colW < 200);

    // ---- zero h buffers (h0 = 0; junk cols stay 0) ----
    for (int i = tid; i < (2 * HSLOT) / 4; i += BLK) ((int*)hbuf)[i] = 0;

    // ---- exact quant LUTs (proven R2-R14, verbatim) ----
    for (int i = tid; i < SIG_SZ; i += BLK) {
        float g = (float)(i - SIG_OFF) * (1.0f / 4096.0f);
        float s = 1.0f / (1.0f + expf(-g));
        float d = s - 1.0f;
        float u = s - fabsf(d);
        float p = 0.5f * (u + 1.0f);
        float t = fminf(fmaxf(p, -0.9921875f), 0.9921875f) * 128.0f;
        float rq = rintf(t);
        int qv = (int)rq;
        if (fabsf(t - rq) > 0.498f) {
            float s2 = 1.0f / (1.0f + (float)exp(-(double)g));
            float d2 = s2 - 1.0f;
            float u2 = s2 - fabsf(d2);
            float p2 = 0.5f * (u2 + 1.0f);
            qv = (int)rintf(fminf(fmaxf(p2, -0.9921875f), 0.9921875f) * 128.0f);
        }
        sigt[i] = (unsigned char)qv;
    }
    for (int i = tid; i < TMAX + 1; i += BLK) {      // |tanh| magnitude table
        float ag = (float)i * (1.0f / 4096.0f);
        float t0 = tanhf(ag);
        float d = t0 - 1.0f;
        float u = t0 - fabsf(d);
        float p = 0.5f * (u + 1.0f);
        float t = fminf(fmaxf(p, -0.9921875f), 0.9921875f) * 128.0f;
        float rq = rintf(t);
        int qv = (int)rq;
        if (fabsf(t - rq) > 0.498f) {
            float t2 = (float)tanh((double)ag);
            float d2 = t2 - 1.0f;
            float u2 = t2 - fabsf(d2);
            float p2 = 0.5f * (u2 + 1.0f);
            qv = (int)rintf(fminf(fmaxf(p2, -0.9921875f), 0.9921875f) * 128.0f);
        }
        tanh8[i] = (signed char)qv;
    }
    if (tid < 255) {                                 // float tanh(nc/32), idx = nc+127
        int nc = tid - 127;
        float t2 = (float)tanh((double)abs(nc) * (1.0 / 32.0));
        float d2 = t2 - 1.0f;
        float u2 = t2 - fabsf(d2);
        float p2 = 0.5f * (u2 + 1.0f);
        int qv = (int)rintf(fminf(fmaxf(p2, -0.9921875f), 0.9921875f) * 128.0f);
        tanc[tid] = (float)(nc < 0 ? -qv : qv);
    }

    // ---- register-resident K64 B fragments (coalesced 16B/lane loads) ----
    v4i Bv[4][5];
    {
        const unsigned long long* bb = wsl + (size_t)(n * 13 + W) * 4 * 5 * 128;
        #pragma unroll
        for (int G = 0; G < 4; ++G)
            #pragma unroll
            for (int ch = 0; ch < 5; ++ch) {
                unsigned long long lo = bb[(size_t)(G * 5 + ch) * 128 + lane * 2];
                unsigned long long hi2 = bb[(size_t)(G * 5 + ch) * 128 + lane * 2 + 1];
                union { unsigned long long u[2]; v4i v; } cv;
                cv.u[0] = lo; cv.u[1] = hi2;
                Bv[G][ch] = cv.v;
            }
    }

    // ---- bias per gate: sigmoid gates bake SIG_OFF; j-gate raw (sign path) --
    int bias[4];
    #pragma unroll
    for (int G = 0; G < 4; ++G) {
        int off = (G == 1) ? 0 : SIG_OFF;
        bias[G] = gok
            ? 32 * (q8f(b_ih[n * 800 + G * 200 + colW]) + q8f(b_hh[n * 800 + G * 200 + colW])) + off
            : off;
    }
    __syncthreads();

    // ---- prestage ALL xq (fp32-faithful, coalesced reads, 48 B rows) ----
    for (int i = tid; i < SEQn * 160; i += BLK) {
        int t = i / 160; int rem = i - t * 160;      // rem = row*40 + k
        int row = rem / 40; int k = rem - row * 40;
        float xv = x[(size_t)t * 10240 + (size_t)b0 * 40 + rem];
        xq[t * 192 + row * XROW + k] = (signed char)xq_f32(xv);
    }

    // lane item identity: row q, col colW, from acc reg 0 of each quad
    float cstf = 0.f;
    const signed char* xqv = xq + arow * XROW + 16 * q;
    const signed char* hbRb = hbuf + arow * HST + 16 * q;
    signed char* wrbb = hbuf + q * HST + colW;
    const v4i zq = (v4i){0, 0, 0, 0};
    __syncthreads();                                 // LUTs + xq ready

    // ---- shadow for t=0: x-chunk MFMA + x32 + bias (elem 0 only) ----
    v4i a0[4];
    {
        v4i ax = *(const v4i*)(xqv);
        #pragma unroll
        for (int G = 0; G < 4; ++G) {
            v4i tx = __builtin_amdgcn_mfma_i32_16x16x64_i8(ax, Bv[G][0], zq, 0, 0, 0);
            v4i t2 = tx;
            t2[0] = tx[0] * 32 + bias[G];
            a0[G] = t2;
        }
    }

    // ======================= time loop (1 barrier/step) =======================
    #pragma clang loop unroll(disable)
    for (int t = 0; t < SEQn; ++t) {
        __syncthreads();                             // h(t) ready

        // h-part: 4 chunks K=64, accumulate onto 32*x + bias
        const signed char* hbR = hbRb + (t & 1) * HSLOT;
        #pragma unroll
        for (int m = 1; m <= 4; ++m) {
            v4i ah = *(const v4i*)(hbR + 64 * (m - 1));
            #pragma unroll
            for (int G = 0; G < 4; ++G)
                a0[G] = __builtin_amdgcn_mfma_i32_16x16x64_i8(ah, Bv[G][m], a0[G], 0, 0, 0);
        }

        // ---- ew: 1 item/lane (row q, col colW) from acc reg 0 ----
        signed char* wrb = wrbb + ((t + 1) & 1) * HSLOT;
        int gi = a0[0][0], gj = a0[1][0], gf = a0[2][0], go = a0[3][0];
        int ix_i = min(max(gi, 0), SIG_SZ - 1);      // clamp = true saturation
        int ix_f = min(max(gf, 0), SIG_SZ - 1);
        int ix_o = min(max(go, 0), SIG_SZ - 1);
        int qi = sigt[ix_i];                         // level-1 gathers (offset-imm)
        int qf = sigt[ix_f];
        int qo = sigt[ix_o];
        int qj = tanh8[min(abs(gj), TMAX)];
        int qjs = (gj < 0) ? -qj : qj;               // odd symmetry, bit-exact
        float gc = rintf(cstf * (float)qf);          // rint(cst*qf/128), exact
        float ai = rintf((float)qi * 0.0078125f * (float)qjs); // rint(qi*qj/128), exact
        float nc = rintf(fminf(fmaxf(fmaf(ai, 0.25f, gc), -127.0f), 127.0f));
        float ac = tanc[(int)(nc + 127.0f)];         // level-2 gather
        cstf = nc * 0.0078125f;
        int nh = (int)rintf(ac * (float)qo * 0.001953125f); // rint(p/512), exact
        if (gok) wrb[0] = (signed char)nh;           // h(t+1)

        // ---- shadow for t+1: x-chunk MFMA + x32 + bias (elem 0 only) ----
        if (t != SEQn - 1) {
            v4i ax = *(const v4i*)(xqv + (t + 1) * 192);
            #pragma unroll
            for (int G = 0; G < 4; ++G) {
                v4i tx = __builtin_amdgcn_mfma_i32_16x16x64_i8(ax, Bv[G][0], zq, 0, 0, 0);
                v4i t2 = tx;
                t2[0] = tx[0] * 32 + bias[G];
                a0[G] = t2;
            }
        }
    }
    __syncthreads();                                 // hT = h(101) in parity 1

    // ---- finFC: out_pre = (S + 32*qfb)/4096, then qp(.., fa2=16) ----
    const signed char* hT = hbuf + 1 * HSLOT;
    if (tid < 64) {
        int b = tid >> 4, oo = (tid >> 3) & 1, ch = tid & 7;
        int S = 0;
        for (int g2 = ch * 25; g2 < ch * 25 + 25; ++g2)
            S += (int)hT[b * HST + g2] * q8f(fw[(n * 200 + g2) * 2 + oo]);
        fcred[tid] = S;
    }
    __syncthreads();
    if (tid < 8) {
        int b = tid >> 1, oo = tid & 1;
        int S = 0;
        #pragma unroll
        for (int ch = 0; ch < 8; ++ch) S += fcred[b * 16 + oo * 8 + ch];
        S += 32 * q8f(fb[n * 2 + oo]);
        float f = fminf(fmaxf((float)S * 0.001953125f, -127.f), 127.f);
        int qo2 = (int)rintf(f);
        vout[tid] = (float)qo2 * 0.125f;
    }
    __syncthreads();
    if (tid < 8) {
        int b = tid >> 1, oo = tid & 1;
        int bg = b0 + b;
        if (n < 4) { if (oo == 0) out[bg * 12 + n] = vout[b * 2] + vout[b * 2 + 1]; }
        else out[bg * 12 + 4 + 2 * (n - 4) + oo] = vout[b * 2 + oo];
    }
}

// ---------------------------------------------------------------------------
extern "C" void kernel_launch(void* const* d_in, const int* in_sizes, int n_in,
                              void* d_out, int out_size, void* d_ws, size_t ws_size,
                              hipStream_t stream) {
    (void)in_sizes; (void)n_in; (void)out_size; (void)ws_size;
    const float* x    = (const float*)d_in[0];
    const float* w_ih = (const float*)d_in[1];
    const float* w_hh = (const float*)d_in[2];
    const float* b_ih = (const float*)d_in[3];
    const float* b_hh = (const float*)d_in[4];
    const float* fw   = (const float*)d_in[15];
    const float* fb   = (const float*)d_in[16];
    unsigned long long* wsl = (unsigned long long*)d_ws;   // 2,129,920 B used

    prep_w<<<1040, 256, 0, stream>>>(w_ih, w_hh, wsl);
    lstm_k<<<512, BLK, 0, stream>>>(x, b_ih, b_hh, fw, fb, wsl, (float*)d_out);
}

// Round 2
// 257.703 us; speedup vs baseline: 1.1986x; 1.1986x over previous
//
#include <hip/hip_runtime.h>
#include <cstdint>

// ===========================================================================
// KWS_LSTM_bmm — exact integer reformulation, fp32-faithful quant decisions.
// R16: R14 structure (256 WGs, 8 rows/WG, 1 WG/CU) + step diet.
//   R15 post-mortem: 2 WGs/CU is register-file-impossible (128 regs/wave x
//   26 waves > 512/SIMD; R13 already knew). Occupancy stayed 37%, two
//   serial passes = 246 us. Reverting to one pass; cutting step cost:
//   * x-fragments read from GLOBAL per step (prep_x pre-quantizes; one
//     dwordx4/lane for t+1 issued at step top, L1-broadcast, latency hidden
//     under h-MFMAs+gathers) -> kills 13 b128 LDS reads/step + 39KB LDS +
//     the upfront staging pass.
//   * A-row remap arow=c>>1: both ew items at FIXED acc regs 0,2 -> no
//     cndmasks; x-shadow fixup on elems 0,2 only.
//   * tanc table dropped: round(128*tanh(|nc|/32)) == tanh8[|nc|*128]
//     (bit-exact, same grid), saturated via min(.,TMAX).
//   LDS 56,864 B. Register budget pinned at 128/wave by launch_bounds(832).
// Exactness: every lattice chain bit-exact in fp32 (numerators < 2^24);
// sigmoid/tanh exact byte LUTs (fast fp32 + 0.498-margin fp64 fallback).
// ===========================================================================

typedef int v4i __attribute__((ext_vector_type(4)));

#define SEQn 101
#define BLK  832              // 13 waves
#define HST  288              // h row stride (2-way banks on b128 reads)
#define HSLOT 2304            // 8 rows
#define SIG_OFF 22720
#define SIG_SZ  41152         // sigmoid q-LUT (idx >= 41152 saturates to 127)
#define TMAX 10527            // |tanh| saturation index

// LDS layout (tables low: gathers fold base into 16-bit ds offset-imm)
#define L_SIGT  0             // u8[41152]
#define L_TANH  41152         // i8[10528]  |tanh| magnitude table
#define L_HBUF  51680         // i8[2][HSLOT] = 4608 B
#define L_FCRED 56288         // int[128]
#define L_VOUT  56800         // float[16]
#define L_TOTAL 56864

#define XG_OFF  2129920       // xq_g base offset in workspace (after wsl)
#define XROW 48               // xq_g row stride (16B-aligned, zero-B spill)

__device__ __forceinline__ int q8f(float v) {        // rint(clip(v*128, ±127))
    float t = fminf(fmaxf(v * 128.0f, -127.0f), 127.0f);
    return (int)rintf(t);
}

// fp32-faithful qp(x, a1=128, 8) on raw inputs
__device__ __forceinline__ int xq_f32(float xv) {
    float ax  = fabsf(xv);
    float d   = ax - 128.0f;
    float u   = ax - fabsf(d);
    float v   = u + 128.0f;
    float p   = 0.5f * v;
    float x01 = p * 0.0078125f;
    x01 = fminf(x01, 0.9921875f);
    int q = (int)rintf(x01 * 128.0f);
    return (xv < 0.0f) ? -q : q;
}

// ---------------- kernel 1: weight quant + K64 B-fragment packing ----------
// wsl[o], o = ((((n*13+t)*4+G)*5+ch)*64 + lane)*2 + h
// fragment byte p = 8h+jj of lane (q,c): k_in_chunk = 16q + 8h + jj
// ch0 = x chunk (k<40 from w_ih); ch1..4 = h chunks (kk = 64(ch-1)+k_in < 200)
__global__ __launch_bounds__(256) void prep_w(const float* __restrict__ w_ih,
                                              const float* __restrict__ w_hh,
                                              unsigned long long* __restrict__ wsl) {
    int o = blockIdx.x * 256 + threadIdx.x;          // 0..266239
    int h = o & 1; int l = (o >> 1) & 63; int r = o >> 7;
    int ch = r % 5; r /= 5;
    int G = r & 3;  r >>= 2;
    int t = r % 13; int n = r / 13;
    int q = l >> 4, cc = l & 15;
    int colW = 16 * t + cc;
    unsigned long long pack = 0ull;
    if (colW < 200) {
        int col = G * 200 + colW;
        #pragma unroll
        for (int jj = 0; jj < 8; ++jj) {
            int k_in = 16 * q + 8 * h + jj;
            int v = 0;
            if (ch == 0) { if (k_in < 40) v = q8f(w_ih[(n * 40 + k_in) * 800 + col]); }
            else { int kk = 64 * (ch - 1) + k_in; if (kk < 200) v = q8f(w_hh[(n * 200 + kk) * 800 + col]); }
            pack |= (unsigned long long)((unsigned)v & 0xffu) << (8 * jj);
        }
    }
    wsl[o] = pack;
}

// ---------------- kernel 1b: input quant into global xq_g -------------------
// xq_g[t][row][48]: k<40 = q8(x), k 40..47 = 0 (zero-weight anyway).
// q=3 fragment reads spill 16B into the next row: weights for k_in 48..63
// are zero, so the spilled bytes are never observed.
__global__ __launch_bounds__(256) void prep_x(const float* __restrict__ x,
                                              signed char* __restrict__ xg) {
    int i = blockIdx.x * 256 + threadIdx.x;          // dword index
    if (i >= SEQn * 256 * 12) return;
    int t = i / 3072; int rem = i - t * 3072;
    int row = rem / 12; int k4 = rem - row * 12;
    unsigned pack = 0u;
    #pragma unroll
    for (int j = 0; j < 4; ++j) {
        int k = 4 * k4 + j;
        int v = 0;
        if (k < 40) v = xq_f32(x[(size_t)(t * 256 + row) * 40 + k]);
        pack |= ((unsigned)v & 0xffu) << (8 * j);
    }
    ((unsigned*)xg)[i] = pack;
}

// ---------------- kernel 2: persistent LSTM ---------------------------------
__global__ __launch_bounds__(BLK) void lstm_k(const float* __restrict__ b_ih,
                                              const float* __restrict__ b_hh,
                                              const float* __restrict__ fw,
                                              const float* __restrict__ fb,
                                              const unsigned long long* __restrict__ wsl,
                                              const signed char* __restrict__ xg,
                                              float* __restrict__ out) {
    __shared__ __align__(16) unsigned char smem[L_TOTAL];
    unsigned char* sigt  = smem + L_SIGT;
    signed char*   tanh8 = (signed char*)(smem + L_TANH);
    signed char*   hbuf  = (signed char*)(smem + L_HBUF);
    int*           fcred = (int*)(smem + L_FCRED);
    float*         vout  = (float*)(smem + L_VOUT);

    const int tid  = threadIdx.x;
    const int n    = blockIdx.x >> 5;                // 0..7
    const int b0   = (blockIdx.x & 31) * 8;          // batch base (8 rows/WG)
    const int W    = tid >> 6;                       // wave 0..12, col-tile W
    const int lane = tid & 63;
    const int q    = lane >> 4;                      // quad
    const int c    = lane & 15;                      // A row idx / B col
    const int arow = c >> 1;                         // batch row held by A row c
    const int colW = 16 * W + c;
    const bool gok = (colW < 200);

    // ---- zero h buffers (h0 = 0; junk cols stay 0) ----
    for (int i = tid; i < (2 * HSLOT) / 4; i += BLK) ((int*)hbuf)[i] = 0;

    // ---- exact quant LUTs (proven R2-R15, verbatim) ----
    for (int i = tid; i < SIG_SZ; i += BLK) {
        float g = (float)(i - SIG_OFF) * (1.0f / 4096.0f);
        float s = 1.0f / (1.0f + expf(-g));
        float d = s - 1.0f;
        float u = s - fabsf(d);
        float p = 0.5f * (u + 1.0f);
        float t = fminf(fmaxf(p, -0.9921875f), 0.9921875f) * 128.0f;
        float rq = rintf(t);
        int qv = (int)rq;
        if (fabsf(t - rq) > 0.498f) {
            float s2 = 1.0f / (1.0f + (float)exp(-(double)g));
            float d2 = s2 - 1.0f;
            float u2 = s2 - fabsf(d2);
            float p2 = 0.5f * (u2 + 1.0f);
            qv = (int)rintf(fminf(fmaxf(p2, -0.9921875f), 0.9921875f) * 128.0f);
        }
        sigt[i] = (unsigned char)qv;
    }
    for (int i = tid; i < TMAX + 1; i += BLK) {      // |tanh| magnitude table
        float ag = (float)i * (1.0f / 4096.0f);
        float t0 = tanhf(ag);
        float d = t0 - 1.0f;
        float u = t0 - fabsf(d);
        float p = 0.5f * (u + 1.0f);
        float t = fminf(fmaxf(p, -0.9921875f), 0.9921875f) * 128.0f;
        float rq = rintf(t);
        int qv = (int)rq;
        if (fabsf(t - rq) > 0.498f) {
            float t2 = (float)tanh((double)ag);
            float d2 = t2 - 1.0f;
            float u2 = t2 - fabsf(d2);
            float p2 = 0.5f * (u2 + 1.0f);
            qv = (int)rintf(fminf(fmaxf(p2, -0.9921875f), 0.9921875f) * 128.0f);
        }
        tanh8[i] = (signed char)qv;
    }

    // ---- register-resident K64 B fragments (coalesced 16B/lane loads) ----
    v4i Bv[4][5];
    {
        const unsigned long long* bb = wsl + (size_t)(n * 13 + W) * 4 * 5 * 128;
        #pragma unroll
        for (int G = 0; G < 4; ++G)
            #pragma unroll
            for (int ch = 0; ch < 5; ++ch) {
                unsigned long long lo = bb[(size_t)(G * 5 + ch) * 128 + lane * 2];
                unsigned long long hi2 = bb[(size_t)(G * 5 + ch) * 128 + lane * 2 + 1];
                union { unsigned long long u[2]; v4i v; } cv;
                cv.u[0] = lo; cv.u[1] = hi2;
                Bv[G][ch] = cv.v;
            }
    }

    // ---- bias per gate: sigmoid gates bake SIG_OFF; j-gate raw (sign path) --
    int bias[4];
    #pragma unroll
    for (int G = 0; G < 4; ++G) {
        int off = (G == 1) ? 0 : SIG_OFF;
        bias[G] = gok
            ? 32 * (q8f(b_ih[n * 800 + G * 200 + colW]) + q8f(b_hh[n * 800 + G * 200 + colW])) + off
            : off;
    }

    // lane item identity: rows 2q+rr (rr=0,1) from acc regs 2rr, col colW
    float cstf[2] = {0.f, 0.f};
    const signed char* xgv  = xg + (size_t)(b0 + arow) * XROW + 16 * q;  // + t*12288
    const signed char* hbRb = hbuf + arow * HST + 16 * q;
    signed char* wrbb = hbuf + (2 * q) * HST + colW;
    const v4i zq = (v4i){0, 0, 0, 0};
    __syncthreads();                                 // LUTs + hbuf ready

    // ---- shadow for t=0: x-chunk MFMA + x32 + bias (elems 0,2 only) ----
    v4i a0[4];
    {
        v4i ax = *(const v4i*)(xgv);                 // global, L1-broadcast
        #pragma unroll
        for (int G = 0; G < 4; ++G) {
            v4i tx = __builtin_amdgcn_mfma_i32_16x16x64_i8(ax, Bv[G][0], zq, 0, 0, 0);
            v4i t2 = tx;
            t2[0] = tx[0] * 32 + bias[G];
            t2[2] = tx[2] * 32 + bias[G];
            a0[G] = t2;
        }
    }

    // ======================= time loop (1 barrier/step) =======================
    #pragma clang loop unroll(disable)
    for (int t = 0; t < SEQn; ++t) {
        __syncthreads();                             // h(t) ready

        // prefetch x fragment for t+1 (VMEM; hidden under h-MFMAs + gathers)
        v4i xnext = zq;
        if (t != SEQn - 1) xnext = *(const v4i*)(xgv + (size_t)(t + 1) * 12288);

        // h-part: 4 chunks K=64, accumulate onto 32*x + bias
        const signed char* hbR = hbRb + (t & 1) * HSLOT;
        #pragma unroll
        for (int m = 1; m <= 4; ++m) {
            v4i ah = *(const v4i*)(hbR + 64 * (m - 1));
            #pragma unroll
            for (int G = 0; G < 4; ++G)
                a0[G] = __builtin_amdgcn_mfma_i32_16x16x64_i8(ah, Bv[G][m], a0[G], 0, 0, 0);
        }

        // ---- ew: 2 items/lane (rows 2q+rr, FIXED acc regs 2rr) ----
        signed char* wrb = wrbb + ((t + 1) & 1) * HSLOT;
        int ix_i[2], ix_f[2], ix_o[2], gj_[2];
        #pragma unroll
        for (int rr = 0; rr < 2; ++rr) {
            int gi = a0[0][2 * rr];
            int gj = a0[1][2 * rr];
            int gf = a0[2][2 * rr];
            int go = a0[3][2 * rr];
            ix_i[rr] = min(max(gi, 0), SIG_SZ - 1);  // clamp = true saturation
            ix_f[rr] = min(max(gf, 0), SIG_SZ - 1);
            ix_o[rr] = min(max(go, 0), SIG_SZ - 1);
            gj_[rr]  = gj;
        }
        int qi[2], qf[2], qo[2], qj[2];
        #pragma unroll
        for (int rr = 0; rr < 2; ++rr) {             // level-1 gathers (offset-imm)
            qi[rr] = sigt[ix_i[rr]];
            qf[rr] = sigt[ix_f[rr]];
            qo[rr] = sigt[ix_o[rr]];
            qj[rr] = tanh8[min(abs(gj_[rr]), TMAX)];
        }

        // ---- shadow for t+1 while gathers are in flight ----
        if (t != SEQn - 1) {
            #pragma unroll
            for (int G = 0; G < 4; ++G) {
                v4i tx = __builtin_amdgcn_mfma_i32_16x16x64_i8(xnext, Bv[G][0], zq, 0, 0, 0);
                v4i t2 = tx;
                t2[0] = tx[0] * 32 + bias[G];
                t2[2] = tx[2] * 32 + bias[G];
                // defer the overwrite of a0 until after ew reads? ew reads
                // were extracted above (gi..go), so a0 is dead here.
                a0[G] = t2;
            }
        }

        float ncv[2];
        #pragma unroll
        for (int rr = 0; rr < 2; ++rr) {
            int qjs = (gj_[rr] < 0) ? -qj[rr] : qj[rr];             // odd symmetry, bit-exact
            float gc = rintf(cstf[rr] * (float)qf[rr]);             // rint(cst*qf/128), exact
            float ai = rintf((float)qi[rr] * 0.0078125f * (float)qjs); // rint(qi*qj/128), exact
            float nc = rintf(fminf(fmaxf(fmaf(ai, 0.25f, gc), -127.0f), 127.0f));
            ncv[rr] = nc;
        }
        int qac[2];
        #pragma unroll
        for (int rr = 0; rr < 2; ++rr) {             // level-2 gathers: tanh8 reuse
            int nci = (int)ncv[rr];                  // exact small int
            int idx = min(abs(nci) << 7, TMAX);      // tanh(|nc|/32) == tanh8[|nc|*128]
            qac[rr] = tanh8[idx];
        }
        #pragma unroll
        for (int rr = 0; rr < 2; ++rr) {
            float ac = (float)((ncv[rr] < 0.0f) ? -qac[rr] : qac[rr]);
            cstf[rr] = ncv[rr] * 0.0078125f;
            int nh = (int)rintf(ac * (float)qo[rr] * 0.001953125f); // rint(p/512), exact
            if (gok) wrb[rr * HST] = (signed char)nh;               // h(t+1), rows 2q+rr
        }
    }
    __syncthreads();                                 // hT = h(101) in parity 1

    // ---- finFC: out_pre = (S + 32*qfb)/4096, then qp(.., fa2=16) ----
    const signed char* hT = hbuf + 1 * HSLOT;
    if (tid < 128) {
        int b = tid >> 4, oo = (tid >> 3) & 1, ch = tid & 7;
        int S = 0;
        for (int g2 = ch * 25; g2 < ch * 25 + 25; ++g2)
            S += (int)hT[b * HST + g2] * q8f(fw[(n * 200 + g2) * 2 + oo]);
        fcred[tid] = S;
    }
    __syncthreads();
    if (tid < 16) {
        int b = tid >> 1, oo = tid & 1;
        int S = 0;
        #pragma unroll
        for (int ch = 0; ch < 8; ++ch) S += fcred[b * 16 + oo * 8 + ch];
        S += 32 * q8f(fb[n * 2 + oo]);
        float f = fminf(fmaxf((float)S * 0.001953125f, -127.f), 127.f);
        int qo2 = (int)rintf(f);
        vout[tid] = (float)qo2 * 0.125f;
    }
    __syncthreads();
    if (tid < 16) {
        int b = tid >> 1, oo = tid & 1;
        int bg = b0 + b;
        if (n < 4) { if (oo == 0) out[bg * 12 + n] = vout[b * 2] + vout[b * 2 + 1]; }
        else out[bg * 12 + 4 + 2 * (n - 4) + oo] = vout[b * 2 + oo];
    }
}

// ---------------------------------------------------------------------------
extern "C" void kernel_launch(void* const* d_in, const int* in_sizes, int n_in,
                              void* d_out, int out_size, void* d_ws, size_t ws_size,
                              hipStream_t stream) {
    (void)in_sizes; (void)n_in; (void)out_size; (void)ws_size;
    const float* x    = (const float*)d_in[0];
    const float* w_ih = (const float*)d_in[1];
    const float* w_hh = (const float*)d_in[2];
    const float* b_ih = (const float*)d_in[3];
    const float* b_hh = (const float*)d_in[4];
    const float* fw   = (const float*)d_in[15];
    const float* fb   = (const float*)d_in[16];
    unsigned long long* wsl = (unsigned long long*)d_ws;   // 2,129,920 B
    signed char* xgq = (signed char*)d_ws + XG_OFF;        // 1,241,104 B

    prep_w<<<1040, 256, 0, stream>>>(w_ih, w_hh, wsl);
    prep_x<<<1212, 256, 0, stream>>>(x, xgq);
    lstm_k<<<256, BLK, 0, stream>>>(b_ih, b_hh, fw, fb, wsl, xgq, (float*)d_out);
}

// Round 3
// 225.283 us; speedup vs baseline: 1.3711x; 1.1439x over previous
//
#include <hip/hip_runtime.h>
#include <cstdint>

// ===========================================================================
// KWS_LSTM_bmm — exact integer reformulation, fp32-faithful quant decisions.
// R17: R16 + tanc-table restore (bank-conflict fix) + x-prefetch hoist.
//   R16 post-mortem: "reuse tanh8 for level-2" put EVERY level-2 gather on
//   bank 16 (addr 41152+128k -> dword 10288+32k, bank const) -> conflicts
//   1.79e7 -> 4.20e7, eating the xq/VALU wins. Fix: dedicated float
//   tanc[255] (stride-4 indexing, banks fully spread) exactly as R14.
//   Also hoist the t+1 x-fragment global load ABOVE the barrier (no LDS
//   dep) so its latency overlaps barrier convergence.
//   Kept from R16: x from global (no xq LDS), fixed acc regs 0/2 (arow=c>>1,
//   no cndmasks), x-shadow fixup on elems 0,2 only.
// Exactness: every lattice chain bit-exact in fp32 (numerators < 2^24);
// sigmoid/tanh exact byte LUTs (fast fp32 + 0.498-margin fp64 fallback).
// ===========================================================================

typedef int v4i __attribute__((ext_vector_type(4)));

#define SEQn 101
#define BLK  832              // 13 waves
#define HST  288              // h row stride (2-way banks on b128 reads)
#define HSLOT 2304            // 8 rows
#define SIG_OFF 22720
#define SIG_SZ  41152         // sigmoid q-LUT (idx >= 41152 saturates to 127)
#define TMAX 10527            // |tanh| saturation index

// LDS layout (tables low: gathers fold base into 16-bit ds offset-imm)
#define L_SIGT  0             // u8[41152]
#define L_TANH  41152         // i8[10528]  |tanh| magnitude table
#define L_TANC  51680         // float[255] (1024 B slot, stride-4 = bank-spread)
#define L_HBUF  52704         // i8[2][HSLOT] = 4608 B
#define L_FCRED 57312         // int[128]
#define L_VOUT  57824         // float[16]
#define L_TOTAL 57888

#define XG_OFF  2129920       // xq_g base offset in workspace (after wsl)
#define XROW 48               // xq_g row stride (16B-aligned, zero-B spill)

__device__ __forceinline__ int q8f(float v) {        // rint(clip(v*128, ±127))
    float t = fminf(fmaxf(v * 128.0f, -127.0f), 127.0f);
    return (int)rintf(t);
}

// fp32-faithful qp(x, a1=128, 8) on raw inputs
__device__ __forceinline__ int xq_f32(float xv) {
    float ax  = fabsf(xv);
    float d   = ax - 128.0f;
    float u   = ax - fabsf(d);
    float v   = u + 128.0f;
    float p   = 0.5f * v;
    float x01 = p * 0.0078125f;
    x01 = fminf(x01, 0.9921875f);
    int q = (int)rintf(x01 * 128.0f);
    return (xv < 0.0f) ? -q : q;
}

// ---------------- kernel 1: weight quant + K64 B-fragment packing ----------
// wsl[o], o = ((((n*13+t)*4+G)*5+ch)*64 + lane)*2 + h
// fragment byte p = 8h+jj of lane (q,c): k_in_chunk = 16q + 8h + jj
// ch0 = x chunk (k<40 from w_ih); ch1..4 = h chunks (kk = 64(ch-1)+k_in < 200)
__global__ __launch_bounds__(256) void prep_w(const float* __restrict__ w_ih,
                                              const float* __restrict__ w_hh,
                                              unsigned long long* __restrict__ wsl) {
    int o = blockIdx.x * 256 + threadIdx.x;          // 0..266239
    int h = o & 1; int l = (o >> 1) & 63; int r = o >> 7;
    int ch = r % 5; r /= 5;
    int G = r & 3;  r >>= 2;
    int t = r % 13; int n = r / 13;
    int q = l >> 4, cc = l & 15;
    int colW = 16 * t + cc;
    unsigned long long pack = 0ull;
    if (colW < 200) {
        int col = G * 200 + colW;
        #pragma unroll
        for (int jj = 0; jj < 8; ++jj) {
            int k_in = 16 * q + 8 * h + jj;
            int v = 0;
            if (ch == 0) { if (k_in < 40) v = q8f(w_ih[(n * 40 + k_in) * 800 + col]); }
            else { int kk = 64 * (ch - 1) + k_in; if (kk < 200) v = q8f(w_hh[(n * 200 + kk) * 800 + col]); }
            pack |= (unsigned long long)((unsigned)v & 0xffu) << (8 * jj);
        }
    }
    wsl[o] = pack;
}

// ---------------- kernel 1b: input quant into global xq_g -------------------
// xq_g[t][row][48]: k<40 = q8(x), k 40..47 = 0 (zero-weight anyway).
// q=3 fragment reads spill 16B into the next row: weights for k_in 48..63
// are zero, so the spilled bytes are never observed.
__global__ __launch_bounds__(256) void prep_x(const float* __restrict__ x,
                                              signed char* __restrict__ xg) {
    int i = blockIdx.x * 256 + threadIdx.x;          // dword index
    if (i >= SEQn * 256 * 12) return;
    int t = i / 3072; int rem = i - t * 3072;
    int row = rem / 12; int k4 = rem - row * 12;
    unsigned pack = 0u;
    #pragma unroll
    for (int j = 0; j < 4; ++j) {
        int k = 4 * k4 + j;
        int v = 0;
        if (k < 40) v = xq_f32(x[(size_t)(t * 256 + row) * 40 + k]);
        pack |= ((unsigned)v & 0xffu) << (8 * j);
    }
    ((unsigned*)xg)[i] = pack;
}

// ---------------- kernel 2: persistent LSTM ---------------------------------
__global__ __launch_bounds__(BLK) void lstm_k(const float* __restrict__ b_ih,
                                              const float* __restrict__ b_hh,
                                              const float* __restrict__ fw,
                                              const float* __restrict__ fb,
                                              const unsigned long long* __restrict__ wsl,
                                              const signed char* __restrict__ xg,
                                              float* __restrict__ out) {
    __shared__ __align__(16) unsigned char smem[L_TOTAL];
    unsigned char* sigt  = smem + L_SIGT;
    signed char*   tanh8 = (signed char*)(smem + L_TANH);
    float*         tanc  = (float*)(smem + L_TANC);
    signed char*   hbuf  = (signed char*)(smem + L_HBUF);
    int*           fcred = (int*)(smem + L_FCRED);
    float*         vout  = (float*)(smem + L_VOUT);

    const int tid  = threadIdx.x;
    const int n    = blockIdx.x >> 5;                // 0..7
    const int b0   = (blockIdx.x & 31) * 8;          // batch base (8 rows/WG)
    const int W    = tid >> 6;                       // wave 0..12, col-tile W
    const int lane = tid & 63;
    const int q    = lane >> 4;                      // quad
    const int c    = lane & 15;                      // A row idx / B col
    const int arow = c >> 1;                         // batch row held by A row c
    const int colW = 16 * W + c;
    const bool gok = (colW < 200);

    // ---- zero h buffers (h0 = 0; junk cols stay 0) ----
    for (int i = tid; i < (2 * HSLOT) / 4; i += BLK) ((int*)hbuf)[i] = 0;

    // ---- exact quant LUTs (proven R2-R16, verbatim) ----
    for (int i = tid; i < SIG_SZ; i += BLK) {
        float g = (float)(i - SIG_OFF) * (1.0f / 4096.0f);
        float s = 1.0f / (1.0f + expf(-g));
        float d = s - 1.0f;
        float u = s - fabsf(d);
        float p = 0.5f * (u + 1.0f);
        float t = fminf(fmaxf(p, -0.9921875f), 0.9921875f) * 128.0f;
        float rq = rintf(t);
        int qv = (int)rq;
        if (fabsf(t - rq) > 0.498f) {
            float s2 = 1.0f / (1.0f + (float)exp(-(double)g));
            float d2 = s2 - 1.0f;
            float u2 = s2 - fabsf(d2);
            float p2 = 0.5f * (u2 + 1.0f);
            qv = (int)rintf(fminf(fmaxf(p2, -0.9921875f), 0.9921875f) * 128.0f);
        }
        sigt[i] = (unsigned char)qv;
    }
    for (int i = tid; i < TMAX + 1; i += BLK) {      // |tanh| magnitude table
        float ag = (float)i * (1.0f / 4096.0f);
        float t0 = tanhf(ag);
        float d = t0 - 1.0f;
        float u = t0 - fabsf(d);
        float p = 0.5f * (u + 1.0f);
        float t = fminf(fmaxf(p, -0.9921875f), 0.9921875f) * 128.0f;
        float rq = rintf(t);
        int qv = (int)rq;
        if (fabsf(t - rq) > 0.498f) {
            float t2 = (float)tanh((double)ag);
            float d2 = t2 - 1.0f;
            float u2 = t2 - fabsf(d2);
            float p2 = 0.5f * (u2 + 1.0f);
            qv = (int)rintf(fminf(fmaxf(p2, -0.9921875f), 0.9921875f) * 128.0f);
        }
        tanh8[i] = (signed char)qv;
    }
    if (tid < 255) {                                 // float tanh(nc/32), idx = nc+127
        int nc = tid - 127;
        float t2 = (float)tanh((double)abs(nc) * (1.0 / 32.0));
        float d2 = t2 - 1.0f;
        float u2 = t2 - fabsf(d2);
        float p2 = 0.5f * (u2 + 1.0f);
        int qv = (int)rintf(fminf(fmaxf(p2, -0.9921875f), 0.9921875f) * 128.0f);
        tanc[tid] = (float)(nc < 0 ? -qv : qv);
    }

    // ---- register-resident K64 B fragments (coalesced 16B/lane loads) ----
    v4i Bv[4][5];
    {
        const unsigned long long* bb = wsl + (size_t)(n * 13 + W) * 4 * 5 * 128;
        #pragma unroll
        for (int G = 0; G < 4; ++G)
            #pragma unroll
            for (int ch = 0; ch < 5; ++ch) {
                unsigned long long lo = bb[(size_t)(G * 5 + ch) * 128 + lane * 2];
                unsigned long long hi2 = bb[(size_t)(G * 5 + ch) * 128 + lane * 2 + 1];
                union { unsigned long long u[2]; v4i v; } cv;
                cv.u[0] = lo; cv.u[1] = hi2;
                Bv[G][ch] = cv.v;
            }
    }

    // ---- bias per gate: sigmoid gates bake SIG_OFF; j-gate raw (sign path) --
    int bias[4];
    #pragma unroll
    for (int G = 0; G < 4; ++G) {
        int off = (G == 1) ? 0 : SIG_OFF;
        bias[G] = gok
            ? 32 * (q8f(b_ih[n * 800 + G * 200 + colW]) + q8f(b_hh[n * 800 + G * 200 + colW])) + off
            : off;
    }

    // lane item identity: rows 2q+rr (rr=0,1) from acc regs 2rr, col colW
    float cstf[2] = {0.f, 0.f};
    const signed char* xgv  = xg + (size_t)(b0 + arow) * XROW + 16 * q;  // + t*12288
    const signed char* hbRb = hbuf + arow * HST + 16 * q;
    signed char* wrbb = hbuf + (2 * q) * HST + colW;
    const v4i zq = (v4i){0, 0, 0, 0};
    __syncthreads();                                 // LUTs + hbuf ready

    // ---- shadow for t=0: x-chunk MFMA + x32 + bias (elems 0,2 only) ----
    v4i a0[4];
    {
        v4i ax = *(const v4i*)(xgv);                 // global, L1-broadcast
        #pragma unroll
        for (int G = 0; G < 4; ++G) {
            v4i tx = __builtin_amdgcn_mfma_i32_16x16x64_i8(ax, Bv[G][0], zq, 0, 0, 0);
            v4i t2 = tx;
            t2[0] = tx[0] * 32 + bias[G];
            t2[2] = tx[2] * 32 + bias[G];
            a0[G] = t2;
        }
    }

    // ======================= time loop (1 barrier/step) =======================
    #pragma clang loop unroll(disable)
    for (int t = 0; t < SEQn; ++t) {
        // prefetch x fragment for t+1 BEFORE the barrier: no LDS dependency,
        // so the VMEM latency overlaps barrier convergence.
        v4i xnext = zq;
        if (t != SEQn - 1) xnext = *(const v4i*)(xgv + (size_t)(t + 1) * 12288);

        __syncthreads();                             // h(t) ready

        // h-part: 4 chunks K=64, accumulate onto 32*x + bias
        const signed char* hbR = hbRb + (t & 1) * HSLOT;
        #pragma unroll
        for (int m = 1; m <= 4; ++m) {
            v4i ah = *(const v4i*)(hbR + 64 * (m - 1));
            #pragma unroll
            for (int G = 0; G < 4; ++G)
                a0[G] = __builtin_amdgcn_mfma_i32_16x16x64_i8(ah, Bv[G][m], a0[G], 0, 0, 0);
        }

        // ---- ew: 2 items/lane (rows 2q+rr, FIXED acc regs 2rr) ----
        signed char* wrb = wrbb + ((t + 1) & 1) * HSLOT;
        int ix_i[2], ix_f[2], ix_o[2], gj_[2];
        #pragma unroll
        for (int rr = 0; rr < 2; ++rr) {
            int gi = a0[0][2 * rr];
            int gj = a0[1][2 * rr];
            int gf = a0[2][2 * rr];
            int go = a0[3][2 * rr];
            ix_i[rr] = min(max(gi, 0), SIG_SZ - 1);  // clamp = true saturation
            ix_f[rr] = min(max(gf, 0), SIG_SZ - 1);
            ix_o[rr] = min(max(go, 0), SIG_SZ - 1);
            gj_[rr]  = gj;
        }
        int qi[2], qf[2], qo[2], qj[2];
        #pragma unroll
        for (int rr = 0; rr < 2; ++rr) {             // level-1 gathers (offset-imm)
            qi[rr] = sigt[ix_i[rr]];
            qf[rr] = sigt[ix_f[rr]];
            qo[rr] = sigt[ix_o[rr]];
            qj[rr] = tanh8[min(abs(gj_[rr]), TMAX)];
        }

        // ---- shadow for t+1 while gathers are in flight (a0 dead here) ----
        if (t != SEQn - 1) {
            #pragma unroll
            for (int G = 0; G < 4; ++G) {
                v4i tx = __builtin_amdgcn_mfma_i32_16x16x64_i8(xnext, Bv[G][0], zq, 0, 0, 0);
                v4i t2 = tx;
                t2[0] = tx[0] * 32 + bias[G];
                t2[2] = tx[2] * 32 + bias[G];
                a0[G] = t2;
            }
        }

        float ncv[2]; int id2[2];
        #pragma unroll
        for (int rr = 0; rr < 2; ++rr) {
            int qjs = (gj_[rr] < 0) ? -qj[rr] : qj[rr];             // odd symmetry, bit-exact
            float gc = rintf(cstf[rr] * (float)qf[rr]);             // rint(cst*qf/128), exact
            float ai = rintf((float)qi[rr] * 0.0078125f * (float)qjs); // rint(qi*qj/128), exact
            float nc = rintf(fminf(fmaxf(fmaf(ai, 0.25f, gc), -127.0f), 127.0f));
            ncv[rr] = nc;
            id2[rr] = (int)(nc + 127.0f);
        }
        float ac[2];
        #pragma unroll
        for (int rr = 0; rr < 2; ++rr) ac[rr] = tanc[id2[rr]];      // level-2: bank-spread
        #pragma unroll
        for (int rr = 0; rr < 2; ++rr) {
            cstf[rr] = ncv[rr] * 0.0078125f;
            int nh = (int)rintf(ac[rr] * (float)qo[rr] * 0.001953125f); // rint(p/512), exact
            if (gok) wrb[rr * HST] = (signed char)nh;               // h(t+1), rows 2q+rr
        }
    }
    __syncthreads();                                 // hT = h(101) in parity 1

    // ---- finFC: out_pre = (S + 32*qfb)/4096, then qp(.., fa2=16) ----
    const signed char* hT = hbuf + 1 * HSLOT;
    if (tid < 128) {
        int b = tid >> 4, oo = (tid >> 3) & 1, ch = tid & 7;
        int S = 0;
        for (int g2 = ch * 25; g2 < ch * 25 + 25; ++g2)
            S += (int)hT[b * HST + g2] * q8f(fw[(n * 200 + g2) * 2 + oo]);
        fcred[tid] = S;
    }
    __syncthreads();
    if (tid < 16) {
        int b = tid >> 1, oo = tid & 1;
        int S = 0;
        #pragma unroll
        for (int ch = 0; ch < 8; ++ch) S += fcred[b * 16 + oo * 8 + ch];
        S += 32 * q8f(fb[n * 2 + oo]);
        float f = fminf(fmaxf((float)S * 0.001953125f, -127.f), 127.f);
        int qo2 = (int)rintf(f);
        vout[tid] = (float)qo2 * 0.125f;
    }
    __syncthreads();
    if (tid < 16) {
        int b = tid >> 1, oo = tid & 1;
        int bg = b0 + b;
        if (n < 4) { if (oo == 0) out[bg * 12 + n] = vout[b * 2] + vout[b * 2 + 1]; }
        else out[bg * 12 + 4 + 2 * (n - 4) + oo] = vout[b * 2 + oo];
    }
}

// ---------------------------------------------------------------------------
extern "C" void kernel_launch(void* const* d_in, const int* in_sizes, int n_in,
                              void* d_out, int out_size, void* d_ws, size_t ws_size,
                              hipStream_t stream) {
    (void)in_sizes; (void)n_in; (void)out_size; (void)ws_size;
    const float* x    = (const float*)d_in[0];
    const float* w_ih = (const float*)d_in[1];
    const float* w_hh = (const float*)d_in[2];
    const float* b_ih = (const float*)d_in[3];
    const float* b_hh = (const float*)d_in[4];
    const float* fw   = (const float*)d_in[15];
    const float* fb   = (const float*)d_in[16];
    unsigned long long* wsl = (unsigned long long*)d_ws;   // 2,129,920 B
    signed char* xgq = (signed char*)d_ws + XG_OFF;        // 1,241,088 B

    prep_w<<<1040, 256, 0, stream>>>(w_ih, w_hh, wsl);
    prep_x<<<1212, 256, 0, stream>>>(x, xgq);
    lstm_k<<<256, BLK, 0, stream>>>(b_ih, b_hh, fw, fb, wsl, xgq, (float*)d_out);
}

// Round 4
// 225.235 us; speedup vs baseline: 1.3714x; 1.0002x over previous
//
#include <hip/hip_runtime.h>
#include <cstdint>

// ===========================================================================
// KWS_LSTM_bmm — exact integer reformulation, fp32-faithful quant decisions.
// R18: R17 + x-prefetch un-hoist + setprio straggler fix + merged prep.
//   R17 post-mortem: tanc restore worked (conflicts 4.2e7->1.52e7, 172.9->
//   143.8us). But the R17 "hoist the x load above the barrier" was a
//   hidden regression: s_barrier forces vmcnt(0) drain, so the load's
//   L2 latency is paid AT the barrier. Fix: issue the xq[t+1] load
//   immediately AFTER the barrier (unconditional, clamped index so the
//   compiler can't sink it) -> ~800 cyc of h-MFMA+gather cover, no
//   barrier crossing before the shadow consumes it.
//   * s_setprio(1) from barrier-exit through gather issue, (0) for the
//     VALU tail: LDS-service stragglers get issue priority over waves
//     already in the ew tail -> compresses per-step straggler spread.
//   * prep_w + prep_x merged into one kernel (one less dispatch gap).
//   Kept: x from global, fixed acc regs 0/2 (arow=c>>1), float tanc[255]
//   (stride-4, bank-spread), 1 barrier/step, 13 waves, 128 regs/wave.
// Exactness: every lattice chain bit-exact in fp32 (numerators < 2^24);
// sigmoid/tanh exact byte LUTs (fast fp32 + 0.498-margin fp64 fallback).
// ===========================================================================

typedef int v4i __attribute__((ext_vector_type(4)));

#define SEQn 101
#define BLK  832              // 13 waves
#define HST  288              // h row stride (2-way banks on b128 reads)
#define HSLOT 2304            // 8 rows
#define SIG_OFF 22720
#define SIG_SZ  41152         // sigmoid q-LUT (idx >= 41152 saturates to 127)
#define TMAX 10527            // |tanh| saturation index

// LDS layout (tables low: gathers fold base into 16-bit ds offset-imm)
#define L_SIGT  0             // u8[41152]
#define L_TANH  41152         // i8[10528]  |tanh| magnitude table
#define L_TANC  51680         // float[255] (1024 B slot, stride-4 = bank-spread)
#define L_HBUF  52704         // i8[2][HSLOT] = 4608 B
#define L_FCRED 57312         // int[128]
#define L_VOUT  57824         // float[16]
#define L_TOTAL 57888

#define XG_OFF  2129920       // xq_g base offset in workspace (after wsl)
#define XROW 48               // xq_g row stride (16B-aligned, zero-B spill)

__device__ __forceinline__ int q8f(float v) {        // rint(clip(v*128, ±127))
    float t = fminf(fmaxf(v * 128.0f, -127.0f), 127.0f);
    return (int)rintf(t);
}

// fp32-faithful qp(x, a1=128, 8) on raw inputs
__device__ __forceinline__ int xq_f32(float xv) {
    float ax  = fabsf(xv);
    float d   = ax - 128.0f;
    float u   = ax - fabsf(d);
    float v   = u + 128.0f;
    float p   = 0.5f * v;
    float x01 = p * 0.0078125f;
    x01 = fminf(x01, 0.9921875f);
    int q = (int)rintf(x01 * 128.0f);
    return (xv < 0.0f) ? -q : q;
}

// ---------------- kernel 1: weight quant + B-frag pack, and x quant --------
// blocks [0,1040): wsl[o], o = ((((n*13+t)*4+G)*5+ch)*64 + lane)*2 + h
//   fragment byte p = 8h+jj of lane (q,c): k_in_chunk = 16q + 8h + jj
//   ch0 = x chunk (k<40, w_ih); ch1..4 = h chunks (kk = 64(ch-1)+k_in < 200)
// blocks [1040,2252): xq_g[t][row][48]: k<40 = q8(x), 40..47 = 0 (zero-B).
//   q=3 fragment reads spill 16B into the next row: weights for k_in 48..63
//   are zero, so the spilled bytes are never observed.
__global__ __launch_bounds__(256) void prep_wx(const float* __restrict__ w_ih,
                                               const float* __restrict__ w_hh,
                                               const float* __restrict__ x,
                                               unsigned long long* __restrict__ wsl,
                                               signed char* __restrict__ xg) {
    int bid = blockIdx.x;
    if (bid < 1040) {
        int o = bid * 256 + threadIdx.x;             // 0..266239
        int h = o & 1; int l = (o >> 1) & 63; int r = o >> 7;
        int ch = r % 5; r /= 5;
        int G = r & 3;  r >>= 2;
        int t = r % 13; int n = r / 13;
        int q = l >> 4, cc = l & 15;
        int colW = 16 * t + cc;
        unsigned long long pack = 0ull;
        if (colW < 200) {
            int col = G * 200 + colW;
            #pragma unroll
            for (int jj = 0; jj < 8; ++jj) {
                int k_in = 16 * q + 8 * h + jj;
                int v = 0;
                if (ch == 0) { if (k_in < 40) v = q8f(w_ih[(n * 40 + k_in) * 800 + col]); }
                else { int kk = 64 * (ch - 1) + k_in; if (kk < 200) v = q8f(w_hh[(n * 200 + kk) * 800 + col]); }
                pack |= (unsigned long long)((unsigned)v & 0xffu) << (8 * jj);
            }
        }
        wsl[o] = pack;
    } else {
        int i = (bid - 1040) * 256 + threadIdx.x;    // dword index
        if (i >= SEQn * 256 * 12) return;
        int t = i / 3072; int rem = i - t * 3072;
        int row = rem / 12; int k4 = rem - row * 12;
        unsigned pack = 0u;
        #pragma unroll
        for (int j = 0; j < 4; ++j) {
            int k = 4 * k4 + j;
            int v = 0;
            if (k < 40) v = xq_f32(x[(size_t)(t * 256 + row) * 40 + k]);
            pack |= ((unsigned)v & 0xffu) << (8 * j);
        }
        ((unsigned*)xg)[i] = pack;
    }
}

// ---------------- kernel 2: persistent LSTM ---------------------------------
__global__ __launch_bounds__(BLK) void lstm_k(const float* __restrict__ b_ih,
                                              const float* __restrict__ b_hh,
                                              const float* __restrict__ fw,
                                              const float* __restrict__ fb,
                                              const unsigned long long* __restrict__ wsl,
                                              const signed char* __restrict__ xg,
                                              float* __restrict__ out) {
    __shared__ __align__(16) unsigned char smem[L_TOTAL];
    unsigned char* sigt  = smem + L_SIGT;
    signed char*   tanh8 = (signed char*)(smem + L_TANH);
    float*         tanc  = (float*)(smem + L_TANC);
    signed char*   hbuf  = (signed char*)(smem + L_HBUF);
    int*           fcred = (int*)(smem + L_FCRED);
    float*         vout  = (float*)(smem + L_VOUT);

    const int tid  = threadIdx.x;
    const int n    = blockIdx.x >> 5;                // 0..7
    const int b0   = (blockIdx.x & 31) * 8;          // batch base (8 rows/WG)
    const int W    = tid >> 6;                       // wave 0..12, col-tile W
    const int lane = tid & 63;
    const int q    = lane >> 4;                      // quad
    const int c    = lane & 15;                      // A row idx / B col
    const int arow = c >> 1;                         // batch row held by A row c
    const int colW = 16 * W + c;
    const bool gok = (colW < 200);

    // ---- zero h buffers (h0 = 0; junk cols stay 0) ----
    for (int i = tid; i < (2 * HSLOT) / 4; i += BLK) ((int*)hbuf)[i] = 0;

    // ---- exact quant LUTs (proven R2-R17, verbatim) ----
    for (int i = tid; i < SIG_SZ; i += BLK) {
        float g = (float)(i - SIG_OFF) * (1.0f / 4096.0f);
        float s = 1.0f / (1.0f + expf(-g));
        float d = s - 1.0f;
        float u = s - fabsf(d);
        float p = 0.5f * (u + 1.0f);
        float t = fminf(fmaxf(p, -0.9921875f), 0.9921875f) * 128.0f;
        float rq = rintf(t);
        int qv = (int)rq;
        if (fabsf(t - rq) > 0.498f) {
            float s2 = 1.0f / (1.0f + (float)exp(-(double)g));
            float d2 = s2 - 1.0f;
            float u2 = s2 - fabsf(d2);
            float p2 = 0.5f * (u2 + 1.0f);
            qv = (int)rintf(fminf(fmaxf(p2, -0.9921875f), 0.9921875f) * 128.0f);
        }
        sigt[i] = (unsigned char)qv;
    }
    for (int i = tid; i < TMAX + 1; i += BLK) {      // |tanh| magnitude table
        float ag = (float)i * (1.0f / 4096.0f);
        float t0 = tanhf(ag);
        float d = t0 - 1.0f;
        float u = t0 - fabsf(d);
        float p = 0.5f * (u + 1.0f);
        float t = fminf(fmaxf(p, -0.9921875f), 0.9921875f) * 128.0f;
        float rq = rintf(t);
        int qv = (int)rq;
        if (fabsf(t - rq) > 0.498f) {
            float t2 = (float)tanh((double)ag);
            float d2 = t2 - 1.0f;
            float u2 = t2 - fabsf(d2);
            float p2 = 0.5f * (u2 + 1.0f);
            qv = (int)rintf(fminf(fmaxf(p2, -0.9921875f), 0.9921875f) * 128.0f);
        }
        tanh8[i] = (signed char)qv;
    }
    if (tid < 255) {                                 // float tanh(nc/32), idx = nc+127
        int nc = tid - 127;
        float t2 = (float)tanh((double)abs(nc) * (1.0 / 32.0));
        float d2 = t2 - 1.0f;
        float u2 = t2 - fabsf(d2);
        float p2 = 0.5f * (u2 + 1.0f);
        int qv = (int)rintf(fminf(fmaxf(p2, -0.9921875f), 0.9921875f) * 128.0f);
        tanc[tid] = (float)(nc < 0 ? -qv : qv);
    }

    // ---- register-resident K64 B fragments (coalesced 16B/lane loads) ----
    v4i Bv[4][5];
    {
        const unsigned long long* bb = wsl + (size_t)(n * 13 + W) * 4 * 5 * 128;
        #pragma unroll
        for (int G = 0; G < 4; ++G)
            #pragma unroll
            for (int ch = 0; ch < 5; ++ch) {
                unsigned long long lo = bb[(size_t)(G * 5 + ch) * 128 + lane * 2];
                unsigned long long hi2 = bb[(size_t)(G * 5 + ch) * 128 + lane * 2 + 1];
                union { unsigned long long u[2]; v4i v; } cv;
                cv.u[0] = lo; cv.u[1] = hi2;
                Bv[G][ch] = cv.v;
            }
    }

    // ---- bias per gate: sigmoid gates bake SIG_OFF; j-gate raw (sign path) --
    int bias[4];
    #pragma unroll
    for (int G = 0; G < 4; ++G) {
        int off = (G == 1) ? 0 : SIG_OFF;
        bias[G] = gok
            ? 32 * (q8f(b_ih[n * 800 + G * 200 + colW]) + q8f(b_hh[n * 800 + G * 200 + colW])) + off
            : off;
    }

    // lane item identity: rows 2q+rr (rr=0,1) from acc regs 2rr, col colW
    float cstf[2] = {0.f, 0.f};
    const signed char* xgv  = xg + (size_t)(b0 + arow) * XROW + 16 * q;  // + t*12288
    const signed char* hbRb = hbuf + arow * HST + 16 * q;
    signed char* wrbb = hbuf + (2 * q) * HST + colW;
    const v4i zq = (v4i){0, 0, 0, 0};
    __syncthreads();                                 // LUTs + hbuf ready

    // ---- shadow for t=0: x-chunk MFMA + x32 + bias (elems 0,2 only) ----
    v4i a0[4];
    {
        v4i ax = *(const v4i*)(xgv);                 // global, L1-broadcast
        #pragma unroll
        for (int G = 0; G < 4; ++G) {
            v4i tx = __builtin_amdgcn_mfma_i32_16x16x64_i8(ax, Bv[G][0], zq, 0, 0, 0);
            v4i t2 = tx;
            t2[0] = tx[0] * 32 + bias[G];
            t2[2] = tx[2] * 32 + bias[G];
            a0[G] = t2;
        }
    }

    // ======================= time loop (1 barrier/step) =======================
    #pragma clang loop unroll(disable)
    for (int t = 0; t < SEQn; ++t) {
        __syncthreads();                             // h(t) ready

        // Issue xq[t+1] load NOW (post-barrier): unconditional clamped index
        // so the compiler can't sink it to the consumer. ~800 cyc of
        // h-MFMA + gather cover; no barrier crossing before use -> the
        // s_barrier vmcnt(0) drain never sees it in flight.
        int tn = (t < SEQn - 1) ? t + 1 : t;
        v4i xnext = *(const v4i*)(xgv + (size_t)tn * 12288);

        __builtin_amdgcn_s_setprio(1);               // LDS-critical front phase

        // h-part: 4 chunks K=64, accumulate onto 32*x + bias
        const signed char* hbR = hbRb + (t & 1) * HSLOT;
        #pragma unroll
        for (int m = 1; m <= 4; ++m) {
            v4i ah = *(const v4i*)(hbR + 64 * (m - 1));
            #pragma unroll
            for (int G = 0; G < 4; ++G)
                a0[G] = __builtin_amdgcn_mfma_i32_16x16x64_i8(ah, Bv[G][m], a0[G], 0, 0, 0);
        }

        // ---- ew: 2 items/lane (rows 2q+rr, FIXED acc regs 2rr) ----
        signed char* wrb = wrbb + ((t + 1) & 1) * HSLOT;
        int ix_i[2], ix_f[2], ix_o[2], gj_[2];
        #pragma unroll
        for (int rr = 0; rr < 2; ++rr) {
            int gi = a0[0][2 * rr];
            int gj = a0[1][2 * rr];
            int gf = a0[2][2 * rr];
            int go = a0[3][2 * rr];
            ix_i[rr] = min(max(gi, 0), SIG_SZ - 1);  // clamp = true saturation
            ix_f[rr] = min(max(gf, 0), SIG_SZ - 1);
            ix_o[rr] = min(max(go, 0), SIG_SZ - 1);
            gj_[rr]  = gj;
        }
        int qi[2], qf[2], qo[2], qj[2];
        #pragma unroll
        for (int rr = 0; rr < 2; ++rr) {             // level-1 gathers (offset-imm)
            qi[rr] = sigt[ix_i[rr]];
            qf[rr] = sigt[ix_f[rr]];
            qo[rr] = sigt[ix_o[rr]];
            qj[rr] = tanh8[min(abs(gj_[rr]), TMAX)];
        }

        __builtin_amdgcn_s_setprio(0);               // tail: yield to stragglers

        // ---- shadow for t+1 while gathers are in flight (a0 dead here) ----
        if (t != SEQn - 1) {
            #pragma unroll
            for (int G = 0; G < 4; ++G) {
                v4i tx = __builtin_amdgcn_mfma_i32_16x16x64_i8(xnext, Bv[G][0], zq, 0, 0, 0);
                v4i t2 = tx;
                t2[0] = tx[0] * 32 + bias[G];
                t2[2] = tx[2] * 32 + bias[G];
                a0[G] = t2;
            }
        }

        float ncv[2]; int id2[2];
        #pragma unroll
        for (int rr = 0; rr < 2; ++rr) {
            int qjs = (gj_[rr] < 0) ? -qj[rr] : qj[rr];             // odd symmetry, bit-exact
            float gc = rintf(cstf[rr] * (float)qf[rr]);             // rint(cst*qf/128), exact
            float ai = rintf((float)qi[rr] * 0.0078125f * (float)qjs); // rint(qi*qj/128), exact
            float nc = rintf(fminf(fmaxf(fmaf(ai, 0.25f, gc), -127.0f), 127.0f));
            ncv[rr] = nc;
            id2[rr] = (int)(nc + 127.0f);
        }
        float ac[2];
        #pragma unroll
        for (int rr = 0; rr < 2; ++rr) ac[rr] = tanc[id2[rr]];      // level-2: bank-spread
        #pragma unroll
        for (int rr = 0; rr < 2; ++rr) {
            cstf[rr] = ncv[rr] * 0.0078125f;
            int nh = (int)rintf(ac[rr] * (float)qo[rr] * 0.001953125f); // rint(p/512), exact
            if (gok) wrb[rr * HST] = (signed char)nh;               // h(t+1), rows 2q+rr
        }
    }
    __syncthreads();                                 // hT = h(101) in parity 1

    // ---- finFC: out_pre = (S + 32*qfb)/4096, then qp(.., fa2=16) ----
    const signed char* hT = hbuf + 1 * HSLOT;
    if (tid < 128) {
        int b = tid >> 4, oo = (tid >> 3) & 1, ch = tid & 7;
        int S = 0;
        for (int g2 = ch * 25; g2 < ch * 25 + 25; ++g2)
            S += (int)hT[b * HST + g2] * q8f(fw[(n * 200 + g2) * 2 + oo]);
        fcred[tid] = S;
    }
    __syncthreads();
    if (tid < 16) {
        int b = tid >> 1, oo = tid & 1;
        int S = 0;
        #pragma unroll
        for (int ch = 0; ch < 8; ++ch) S += fcred[b * 16 + oo * 8 + ch];
        S += 32 * q8f(fb[n * 2 + oo]);
        float f = fminf(fmaxf((float)S * 0.001953125f, -127.f), 127.f);
        int qo2 = (int)rintf(f);
        vout[tid] = (float)qo2 * 0.125f;
    }
    __syncthreads();
    if (tid < 16) {
        int b = tid >> 1, oo = tid & 1;
        int bg = b0 + b;
        if (n < 4) { if (oo == 0) out[bg * 12 + n] = vout[b * 2] + vout[b * 2 + 1]; }
        else out[bg * 12 + 4 + 2 * (n - 4) + oo] = vout[b * 2 + oo];
    }
}

// ---------------------------------------------------------------------------
extern "C" void kernel_launch(void* const* d_in, const int* in_sizes, int n_in,
                              void* d_out, int out_size, void* d_ws, size_t ws_size,
                              hipStream_t stream) {
    (void)in_sizes; (void)n_in; (void)out_size; (void)ws_size;
    const float* x    = (const float*)d_in[0];
    const float* w_ih = (const float*)d_in[1];
    const float* w_hh = (const float*)d_in[2];
    const float* b_ih = (const float*)d_in[3];
    const float* b_hh = (const float*)d_in[4];
    const float* fw   = (const float*)d_in[15];
    const float* fb   = (const float*)d_in[16];
    unsigned long long* wsl = (unsigned long long*)d_ws;   // 2,129,920 B
    signed char* xgq = (signed char*)d_ws + XG_OFF;        // 1,241,088 B

    prep_wx<<<2252, 256, 0, stream>>>(w_ih, w_hh, x, wsl, xgq);
    lstm_k<<<256, BLK, 0, stream>>>(b_ih, b_hh, fw, fb, wsl, xgq, (float*)d_out);
}